// Round 2
// baseline (1004.559 us; speedup 1.0000x reference)
//
#include <hip/hip_runtime.h>

// GCN scatter-aggregate, fp32 end-to-end:
//   h = x @ W                          [100000, 256] x [256, 128]
//   out[r] = sum_e dis[r]*dis[c] * h[c]  (scatter over 1.6M edges) + bias
// Inputs (harness order): x fp32 [N,256], edge_index int32 [2,E],
//                         W fp32 [256,128], bias fp32 [128]. Output fp32 [N,128].

#define N_FEAT 256
#define N_HID  128
#define BN 64    // nodes per gemm block
#define KC 64    // k-chunk staged in LDS

// ---- out[n][d] = bias[d] (also serves as the zero-init for the scatter) ----
__global__ void k_init(const float4* __restrict__ bias4,
                       float4* __restrict__ out4, int n4) {
    int i = blockIdx.x * blockDim.x + threadIdx.x;
    if (i < n4) out4[i] = bias4[i & 31];   // 128 floats = 32 float4 per row
}

// ---- deg[row[e]] += 1 -------------------------------------------------------
__global__ void k_deg(const int* __restrict__ ei, int* __restrict__ deg, int E) {
    int e = blockIdx.x * blockDim.x + threadIdx.x;
    if (e < E) atomicAdd(&deg[ei[e]], 1);
}

// ---- dis = deg>0 ? rsqrt(deg) : 0 ------------------------------------------
__global__ void k_dis(const int* __restrict__ deg, float* __restrict__ dis, int N) {
    int i = blockIdx.x * blockDim.x + threadIdx.x;
    if (i < N) {
        int d = deg[i];
        dis[i] = (d > 0) ? rsqrtf((float)d) : 0.0f;
    }
}

// ---- h = x @ W, tiled -------------------------------------------------------
// Block: 256 threads = 32 col-groups (4 cols) x 8 node-groups (8 nodes).
// Per block: 64 nodes x 128 cols. x staged in LDS transposed [k][node] with an
// XOR-8 swizzle (breaks the stride-64 16-way write conflict down to 4-way while
// keeping 8-node reads contiguous for b128). W chunk (64x128 fp32 = 32KB) is
// L1-resident — read as float4 from global each k.
__global__ __launch_bounds__(256) void k_gemm(const float* __restrict__ x,
                                              const float* __restrict__ W,
                                              float* __restrict__ h, int N) {
    __shared__ float xsT[KC * BN];   // 16 KB
    const int t  = threadIdx.x;
    const int cg = t & 31;           // cols 4cg .. 4cg+3
    const int ng = t >> 5;           // nodes 8ng .. 8ng+7
    const int node0 = blockIdx.x * BN;

    float acc[8][4] = {};

    const float4* x4 = (const float4*)x;
    const float4* W4 = (const float4*)W;

    for (int k0 = 0; k0 < N_FEAT; k0 += KC) {
        __syncthreads();   // previous chunk fully consumed
        // stage 64 nodes x 64 k = 1024 float4, 4 per thread
#pragma unroll
        for (int r = 0; r < 4; ++r) {
            int idx = t + 256 * r;
            int nd  = idx >> 4;       // 0..63
            int kq  = idx & 15;       // float4 index within chunk
            int gn  = node0 + nd;
            float4 v = (gn < N) ? x4[gn * (N_FEAT / 4) + (k0 >> 2) + kq]
                                : make_float4(0.f, 0.f, 0.f, 0.f);
            int kk = 4 * kq;
            int sn = nd ^ (8 * (kq & 7));   // swizzle: 8*((k>>2)&7), k=4kq+i
            xsT[(kk + 0) * BN + sn] = v.x;
            xsT[(kk + 1) * BN + sn] = v.y;
            xsT[(kk + 2) * BN + sn] = v.z;
            xsT[(kk + 3) * BN + sn] = v.w;
        }
        __syncthreads();

#pragma unroll 4
        for (int k = 0; k < KC; ++k) {
            float4 w = W4[(k0 + k) * (N_HID / 4) + cg];   // L1 hit (32KB chunk)
            int s = 8 * ((k >> 2) & 7);
            const float* xr = &xsT[k * BN + ((8 * ng) ^ s)];
            float4 a = *(const float4*)(xr);
            float4 b = *(const float4*)(xr + 4);
            float xv[8] = {a.x, a.y, a.z, a.w, b.x, b.y, b.z, b.w};
#pragma unroll
            for (int n = 0; n < 8; ++n) {
                acc[n][0] = fmaf(xv[n], w.x, acc[n][0]);
                acc[n][1] = fmaf(xv[n], w.y, acc[n][1]);
                acc[n][2] = fmaf(xv[n], w.z, acc[n][2]);
                acc[n][3] = fmaf(xv[n], w.w, acc[n][3]);
            }
        }
    }

#pragma unroll
    for (int n = 0; n < 8; ++n) {
        int gn = node0 + 8 * ng + n;
        if (gn < N)
            ((float4*)h)[gn * (N_HID / 4) + cg] =
                make_float4(acc[n][0], acc[n][1], acc[n][2], acc[n][3]);
    }
}

// ---- scatter: out[r][d] += dis[r]*dis[c] * h[c][d] --------------------------
// 256 threads = 2 edges x 128 dims. One hw f32 atomic per element into d_out.
__global__ __launch_bounds__(256) void k_scatter(const int* __restrict__ ei,
                                                 const float* __restrict__ h,
                                                 const float* __restrict__ dis,
                                                 float* __restrict__ out, int E) {
    int e = blockIdx.x * 2 + (threadIdx.x >> 7);
    int d = threadIdx.x & 127;
    if (e >= E) return;
    int r = ei[e];
    int c = ei[E + e];
    float norm = dis[r] * dis[c];
    float v = norm * h[(size_t)c * N_HID + d];
    unsafeAtomicAdd(out + (size_t)r * N_HID + d, v);   // global_atomic_add_f32
}

extern "C" void kernel_launch(void* const* d_in, const int* in_sizes, int n_in,
                              void* d_out, int out_size, void* d_ws, size_t ws_size,
                              hipStream_t stream) {
    const float* x    = (const float*)d_in[0];   // fp32 [N,256]
    const int*   ei   = (const int*)d_in[1];     // int32 [2,E]
    const float* W    = (const float*)d_in[2];   // fp32 [256,128]
    const float* bias = (const float*)d_in[3];   // fp32 [128]

    const int N = in_sizes[0] / N_FEAT;   // 100000
    const int E = in_sizes[1] / 2;        // 1600000

    // workspace: deg (N i32) | dis (N f32) | h (N*128 f32)  ~= 52 MB
    char* ws = (char*)d_ws;
    int*   deg = (int*)ws;
    float* dis = (float*)(ws + (size_t)N * 4);
    float* h   = (float*)(ws + (size_t)N * 8);

    hipMemsetAsync(deg, 0, (size_t)N * 4, stream);

    int n4 = N * N_HID / 4;
    k_init<<<(n4 + 255) / 256, 256, 0, stream>>>((const float4*)bias,
                                                 (float4*)d_out, n4);
    k_deg<<<(E + 255) / 256, 256, 0, stream>>>(ei, deg, E);
    k_dis<<<(N + 255) / 256, 256, 0, stream>>>(deg, dis, N);
    k_gemm<<<(N + BN - 1) / BN, 256, 0, stream>>>(x, W, h, N);
    k_scatter<<<(E + 1) / 2, 256, 0, stream>>>(ei, h, dis, (float*)d_out, E);
}

// Round 3
// 600.615 us; speedup vs baseline: 1.6725x; 1.6725x over previous
//
#include <hip/hip_runtime.h>

// GCN scatter-aggregate, fp32 end-to-end:
//   h[n]  = dis[n] * (x[n] @ W)            (dis = deg^-1/2 folded into GEMM)
//   out[r] = dis[r] * sum_{e:dst=r} h[src_e] + bias   (atomic-free segment sum
//            over edges counting-sorted by destination)
// Inputs: x fp32 [N,256], edge_index int32 [2,E] (row=dst, col=src),
//         W fp32 [256,128], bias fp32 [128]. Output fp32 [N,128].

#define N_FEAT 256
#define N_HID  128
#define BN 64    // nodes per gemm block
#define KC 64    // k-chunk staged in LDS

// ---- deg[dst[e]] += 1 -------------------------------------------------------
__global__ void k_deg(const int* __restrict__ ei, int* __restrict__ deg, int E) {
    int e = blockIdx.x * blockDim.x + threadIdx.x;
    if (e < E) atomicAdd(&deg[ei[e]], 1);
}

// ---- dis = deg>0 ? rsqrt(deg) : 0 ------------------------------------------
__global__ void k_dis(const int* __restrict__ deg, float* __restrict__ dis, int N) {
    int i = blockIdx.x * blockDim.x + threadIdx.x;
    if (i < N) {
        int d = deg[i];
        dis[i] = (d > 0) ? rsqrtf((float)d) : 0.0f;
    }
}

// ---- scan stage 1: per-block (1024 elems) sums ------------------------------
__global__ __launch_bounds__(256) void k_scan_blocks(const int* __restrict__ deg,
                                                     int* __restrict__ part, int N) {
    __shared__ int red[256];
    int t = threadIdx.x;
    int base = blockIdx.x * 1024 + t * 4;
    int s = 0;
#pragma unroll
    for (int j = 0; j < 4; ++j) { int i = base + j; if (i < N) s += deg[i]; }
    red[t] = s;
    __syncthreads();
    for (int off = 128; off > 0; off >>= 1) {
        if (t < off) red[t] += red[t + off];
        __syncthreads();
    }
    if (t == 0) part[blockIdx.x] = red[0];
}

// ---- scan stage 2: exclusive scan of the ~98 partials (single thread) -------
__global__ void k_scan_top(int* __restrict__ part, int G,
                           int* __restrict__ rowptr, int N) {
    if (threadIdx.x == 0 && blockIdx.x == 0) {
        int run = 0;
        for (int i = 0; i < G; ++i) { int v = part[i]; part[i] = run; run += v; }
        rowptr[N] = run;   // == E
    }
}

// ---- scan stage 3: rowptr[i] (and cursor copy) ------------------------------
__global__ __launch_bounds__(256) void k_scan_out(const int* __restrict__ deg,
                                                  const int* __restrict__ part,
                                                  int* __restrict__ rowptr,
                                                  int* __restrict__ cursor, int N) {
    __shared__ int sc[256];
    int t = threadIdx.x;
    int base = blockIdx.x * 1024 + t * 4;
    int v[4]; int s = 0;
#pragma unroll
    for (int j = 0; j < 4; ++j) { int i = base + j; v[j] = (i < N) ? deg[i] : 0; s += v[j]; }
    sc[t] = s;
    __syncthreads();
    for (int off = 1; off < 256; off <<= 1) {     // inclusive Hillis-Steele
        int a = sc[t];
        int b = (t >= off) ? sc[t - off] : 0;
        __syncthreads();
        sc[t] = a + b;
        __syncthreads();
    }
    int run = sc[t] - s + part[blockIdx.x];       // exclusive offset for this thread
#pragma unroll
    for (int j = 0; j < 4; ++j) {
        int i = base + j;
        if (i < N) { rowptr[i] = run; cursor[i] = run; run += v[j]; }
    }
}

// ---- bucket edges by dst: srcs[cursor[dst]++] = src -------------------------
__global__ void k_bucket(const int* __restrict__ ei, int* __restrict__ cursor,
                         int* __restrict__ srcs, int E) {
    int e = blockIdx.x * blockDim.x + threadIdx.x;
    if (e < E) {
        int d = ei[e];
        int pos = atomicAdd(&cursor[d], 1);
        srcs[pos] = ei[E + e];
    }
}

// ---- h = dis[n] * (x @ W), tiled --------------------------------------------
__global__ __launch_bounds__(256) void k_gemm(const float* __restrict__ x,
                                              const float* __restrict__ W,
                                              const float* __restrict__ dis,
                                              float* __restrict__ h, int N) {
    __shared__ float xsT[KC * BN];   // 16 KB
    const int t  = threadIdx.x;
    const int cg = t & 31;           // cols 4cg .. 4cg+3
    const int ng = t >> 5;           // nodes 8ng .. 8ng+7
    const int node0 = blockIdx.x * BN;

    float acc[8][4] = {};

    const float4* x4 = (const float4*)x;
    const float4* W4 = (const float4*)W;

    for (int k0 = 0; k0 < N_FEAT; k0 += KC) {
        __syncthreads();
#pragma unroll
        for (int r = 0; r < 4; ++r) {
            int idx = t + 256 * r;
            int nd  = idx >> 4;
            int kq  = idx & 15;
            int gn  = node0 + nd;
            float4 v = (gn < N) ? x4[gn * (N_FEAT / 4) + (k0 >> 2) + kq]
                                : make_float4(0.f, 0.f, 0.f, 0.f);
            int kk = 4 * kq;
            int sn = nd ^ (8 * (kq & 7));
            xsT[(kk + 0) * BN + sn] = v.x;
            xsT[(kk + 1) * BN + sn] = v.y;
            xsT[(kk + 2) * BN + sn] = v.z;
            xsT[(kk + 3) * BN + sn] = v.w;
        }
        __syncthreads();

#pragma unroll 4
        for (int k = 0; k < KC; ++k) {
            float4 w = W4[(k0 + k) * (N_HID / 4) + cg];
            int s = 8 * ((k >> 2) & 7);
            const float* xr = &xsT[k * BN + ((8 * ng) ^ s)];
            float4 a = *(const float4*)(xr);
            float4 b = *(const float4*)(xr + 4);
            float xv[8] = {a.x, a.y, a.z, a.w, b.x, b.y, b.z, b.w};
#pragma unroll
            for (int n = 0; n < 8; ++n) {
                acc[n][0] = fmaf(xv[n], w.x, acc[n][0]);
                acc[n][1] = fmaf(xv[n], w.y, acc[n][1]);
                acc[n][2] = fmaf(xv[n], w.z, acc[n][2]);
                acc[n][3] = fmaf(xv[n], w.w, acc[n][3]);
            }
        }
    }

#pragma unroll
    for (int n = 0; n < 8; ++n) {
        int gn = node0 + 8 * ng + n;
        if (gn < N) {
            float dn = dis[gn];
            ((float4*)h)[gn * (N_HID / 4) + cg] =
                make_float4(dn * acc[n][0], dn * acc[n][1],
                            dn * acc[n][2], dn * acc[n][3]);
        }
    }
}

// ---- atomic-free aggregation: out[n] = dis[n] * sum(h[srcs]) + bias ---------
// 256 threads = 2 nodes x 128 dims; contiguous 512B gathers, one write per node.
__global__ __launch_bounds__(256) void k_aggr(const int* __restrict__ rowptr,
                                              const int* __restrict__ srcs,
                                              const float* __restrict__ h,
                                              const float* __restrict__ dis,
                                              const float* __restrict__ bias,
                                              float* __restrict__ out, int N) {
    int n = blockIdx.x * 2 + (threadIdx.x >> 7);
    int d = threadIdx.x & 127;
    if (n >= N) return;
    int i   = rowptr[n];
    int end = rowptr[n + 1];
    float a = 0.f;
    for (; i + 4 <= end; i += 4) {               // 4 independent gathers in flight
        int c0 = srcs[i], c1 = srcs[i + 1], c2 = srcs[i + 2], c3 = srcs[i + 3];
        float v0 = h[(size_t)c0 * N_HID + d];
        float v1 = h[(size_t)c1 * N_HID + d];
        float v2 = h[(size_t)c2 * N_HID + d];
        float v3 = h[(size_t)c3 * N_HID + d];
        a += v0; a += v1; a += v2; a += v3;
    }
    for (; i < end; ++i) a += h[(size_t)srcs[i] * N_HID + d];
    out[(size_t)n * N_HID + d] = dis[n] * a + bias[d];
}

extern "C" void kernel_launch(void* const* d_in, const int* in_sizes, int n_in,
                              void* d_out, int out_size, void* d_ws, size_t ws_size,
                              hipStream_t stream) {
    const float* x    = (const float*)d_in[0];   // fp32 [N,256]
    const int*   ei   = (const int*)d_in[1];     // int32 [2,E]
    const float* W    = (const float*)d_in[2];   // fp32 [256,128]
    const float* bias = (const float*)d_in[3];   // fp32 [128]

    const int N = in_sizes[0] / N_FEAT;   // 100000
    const int E = in_sizes[1] / 2;        // 1600000

    // workspace layout (~59 MB)
    char* ws = (char*)d_ws;
    size_t off = 0;
    int*   deg    = (int*)(ws + off);   off += (size_t)N * 4;
    float* dis    = (float*)(ws + off); off += (size_t)N * 4;
    int*   rowptr = (int*)(ws + off);   off += (size_t)(N + 1) * 4 + 12;  // pad to 16
    int*   cursor = (int*)(ws + off);   off += (size_t)N * 4;
    int*   part   = (int*)(ws + off);   off += 512;
    int*   srcs   = (int*)(ws + off);   off += (size_t)E * 4;
    float* h      = (float*)(ws + off); // N*128 fp32, 16B-aligned

    hipMemsetAsync(deg, 0, (size_t)N * 4, stream);

    const int G = (N + 1023) / 1024;     // 98 scan blocks
    k_deg<<<(E + 255) / 256, 256, 0, stream>>>(ei, deg, E);
    k_dis<<<(N + 255) / 256, 256, 0, stream>>>(deg, dis, N);
    k_scan_blocks<<<G, 256, 0, stream>>>(deg, part, N);
    k_scan_top<<<1, 64, 0, stream>>>(part, G, rowptr, N);
    k_scan_out<<<G, 256, 0, stream>>>(deg, part, rowptr, cursor, N);
    k_bucket<<<(E + 255) / 256, 256, 0, stream>>>(ei, cursor, srcs, E);
    k_gemm<<<(N + BN - 1) / BN, 256, 0, stream>>>(x, W, dis, h, N);
    k_aggr<<<(N + 1) / 2, 256, 0, stream>>>(rowptr, srcs, h, dis, bias,
                                            (float*)d_out, N);
}

// Round 5
// 533.462 us; speedup vs baseline: 1.8831x; 1.1259x over previous
//
#include <hip/hip_runtime.h>

// GCN scatter-aggregate:
//   h[n]  = bf16( dis[n] * (x[n] @ W) )     (fp32 compute, bf16 storage)
//   out[r] = dis[r] * sum_{e:dst=r} h[src_e] + bias   (fp32 accumulate,
//            atomic-free segment sum over dst-counting-sorted edges)
// Inputs: x fp32 [N,256], edge_index int32 [2,E] (row=dst, col=src),
//         W fp32 [256,128], bias fp32 [128]. Output fp32 [N,128].

#define N_FEAT 256
#define N_HID  128
#define BN 64    // nodes per gemm block
#define KC 64    // k-chunk staged in LDS

typedef float fx4 __attribute__((ext_vector_type(4)));   // clang-native vec4

__device__ __forceinline__ float bf2f(unsigned int u) {
    return __uint_as_float(u << 16);
}
__device__ __forceinline__ unsigned int f2bf(float f) {
    unsigned int u = __float_as_uint(f);
    return (u + 0x7FFFu + ((u >> 16) & 1u)) >> 16;  // round-nearest-even
}

// ---- deg[dst[e]] += 1 -------------------------------------------------------
__global__ void k_deg(const int* __restrict__ ei, int* __restrict__ deg, int E) {
    int e = blockIdx.x * blockDim.x + threadIdx.x;
    if (e < E) atomicAdd(&deg[ei[e]], 1);
}

// ---- scan stage 1: per-block (1024 elems) sums ------------------------------
__global__ __launch_bounds__(256) void k_scan_blocks(const int* __restrict__ deg,
                                                     int* __restrict__ part, int N) {
    __shared__ int red[256];
    int t = threadIdx.x;
    int base = blockIdx.x * 1024 + t * 4;
    int s = 0;
#pragma unroll
    for (int j = 0; j < 4; ++j) { int i = base + j; if (i < N) s += deg[i]; }
    red[t] = s;
    __syncthreads();
    for (int off = 128; off > 0; off >>= 1) {
        if (t < off) red[t] += red[t + off];
        __syncthreads();
    }
    if (t == 0) part[blockIdx.x] = red[0];
}

// ---- scan stage 2: exclusive scan of the ~98 partials (single thread) -------
__global__ void k_scan_top(int* __restrict__ part, int G,
                           int* __restrict__ rowptr, int N) {
    if (threadIdx.x == 0 && blockIdx.x == 0) {
        int run = 0;
        for (int i = 0; i < G; ++i) { int v = part[i]; part[i] = run; run += v; }
        rowptr[N] = run;   // == E
    }
}

// ---- scan stage 3: rowptr / cursor / dis (k_dis fused here) -----------------
__global__ __launch_bounds__(256) void k_scan_out(const int* __restrict__ deg,
                                                  const int* __restrict__ part,
                                                  int* __restrict__ rowptr,
                                                  int* __restrict__ cursor,
                                                  float* __restrict__ dis, int N) {
    __shared__ int sc[256];
    int t = threadIdx.x;
    int base = blockIdx.x * 1024 + t * 4;
    int v[4]; int s = 0;
#pragma unroll
    for (int j = 0; j < 4; ++j) { int i = base + j; v[j] = (i < N) ? deg[i] : 0; s += v[j]; }
    sc[t] = s;
    __syncthreads();
    for (int off = 1; off < 256; off <<= 1) {     // inclusive Hillis-Steele
        int a = sc[t];
        int b = (t >= off) ? sc[t - off] : 0;
        __syncthreads();
        sc[t] = a + b;
        __syncthreads();
    }
    int run = sc[t] - s + part[blockIdx.x];       // exclusive offset for this thread
#pragma unroll
    for (int j = 0; j < 4; ++j) {
        int i = base + j;
        if (i < N) {
            rowptr[i] = run; cursor[i] = run; run += v[j];
            dis[i] = (v[j] > 0) ? rsqrtf((float)v[j]) : 0.0f;
        }
    }
}

// ---- bucket edges by dst: srcs[cursor[dst]++] = src -------------------------
__global__ void k_bucket(const int* __restrict__ ei, int* __restrict__ cursor,
                         int* __restrict__ srcs, int E) {
    int e = blockIdx.x * blockDim.x + threadIdx.x;
    if (e < E) {
        int d = ei[e];
        int pos = atomicAdd(&cursor[d], 1);
        srcs[pos] = ei[E + e];
    }
}

// ---- h = bf16(dis[n] * (x @ W)), tiled --------------------------------------
__global__ __launch_bounds__(256) void k_gemm(const float* __restrict__ x,
                                              const float* __restrict__ W,
                                              const float* __restrict__ dis,
                                              unsigned int* __restrict__ h2, int N) {
    __shared__ float xsT[KC * BN];   // 16 KB
    const int t  = threadIdx.x;
    const int cg = t & 31;           // cols 4cg .. 4cg+3
    const int ng = t >> 5;           // nodes 8ng .. 8ng+7
    const int node0 = blockIdx.x * BN;

    float acc[8][4] = {};

    const fx4*    x4 = (const fx4*)x;
    const float4* W4 = (const float4*)W;

    for (int k0 = 0; k0 < N_FEAT; k0 += KC) {
        __syncthreads();
#pragma unroll
        for (int r = 0; r < 4; ++r) {
            int idx = t + 256 * r;
            int nd  = idx >> 4;
            int kq  = idx & 15;
            int gn  = node0 + nd;
            fx4 v = (gn < N)
                ? __builtin_nontemporal_load(&x4[gn * (N_FEAT / 4) + (k0 >> 2) + kq])
                : (fx4){0.f, 0.f, 0.f, 0.f};
            int kk = 4 * kq;
            int sn = nd ^ (8 * (kq & 7));
            xsT[(kk + 0) * BN + sn] = v.x;
            xsT[(kk + 1) * BN + sn] = v.y;
            xsT[(kk + 2) * BN + sn] = v.z;
            xsT[(kk + 3) * BN + sn] = v.w;
        }
        __syncthreads();

#pragma unroll 4
        for (int k = 0; k < KC; ++k) {
            float4 w = W4[(k0 + k) * (N_HID / 4) + cg];
            int s = 8 * ((k >> 2) & 7);
            const float* xr = &xsT[k * BN + ((8 * ng) ^ s)];
            float4 a = *(const float4*)(xr);
            float4 b = *(const float4*)(xr + 4);
            float xv[8] = {a.x, a.y, a.z, a.w, b.x, b.y, b.z, b.w};
#pragma unroll
            for (int n = 0; n < 8; ++n) {
                acc[n][0] = fmaf(xv[n], w.x, acc[n][0]);
                acc[n][1] = fmaf(xv[n], w.y, acc[n][1]);
                acc[n][2] = fmaf(xv[n], w.z, acc[n][2]);
                acc[n][3] = fmaf(xv[n], w.w, acc[n][3]);
            }
        }
    }

#pragma unroll
    for (int n = 0; n < 8; ++n) {
        int gn = node0 + 8 * ng + n;
        if (gn < N) {
            float dn = dis[gn];
            uint2 p;
            p.x = f2bf(dn * acc[n][0]) | (f2bf(dn * acc[n][1]) << 16);
            p.y = f2bf(dn * acc[n][2]) | (f2bf(dn * acc[n][3]) << 16);
            ((uint2*)h2)[(size_t)gn * 32 + cg] = p;   // row = 32 uint2 = 256 B
        }
    }
}

// ---- atomic-free aggregation: out[n] = dis[n] * sum(h[srcs]) + bias ---------
// 256 threads = 4 nodes x 64 lanes; lane loads one bf16-pair dword per edge
// (64 lanes = one full 256B row). 8 edges in flight per lane.
__global__ __launch_bounds__(256) void k_aggr(const int* __restrict__ rowptr,
                                              const int* __restrict__ srcs,
                                              const unsigned int* __restrict__ h2,
                                              const float* __restrict__ dis,
                                              const float* __restrict__ bias,
                                              float2* __restrict__ out2, int N) {
    int n    = blockIdx.x * 4 + (threadIdx.x >> 6);
    int lane = threadIdx.x & 63;
    if (n >= N) return;
    int i   = rowptr[n];
    int end = rowptr[n + 1];
    float ax = 0.f, ay = 0.f;
    for (; i + 8 <= end; i += 8) {
        int c[8];
#pragma unroll
        for (int j = 0; j < 8; ++j) c[j] = srcs[i + j];
        unsigned int p[8];
#pragma unroll
        for (int j = 0; j < 8; ++j) p[j] = h2[(size_t)c[j] * 64 + lane];
#pragma unroll
        for (int j = 0; j < 8; ++j) {
            ax += bf2f(p[j] & 0xFFFFu);
            ay += bf2f(p[j] >> 16);
        }
    }
    for (; i < end; ++i) {
        unsigned int p = h2[(size_t)srcs[i] * 64 + lane];
        ax += bf2f(p & 0xFFFFu);
        ay += bf2f(p >> 16);
    }
    float dn = dis[n];
    float2 b = ((const float2*)bias)[lane];
    float2 o; o.x = dn * ax + b.x; o.y = dn * ay + b.y;
    out2[(size_t)n * 64 + lane] = o;
}

extern "C" void kernel_launch(void* const* d_in, const int* in_sizes, int n_in,
                              void* d_out, int out_size, void* d_ws, size_t ws_size,
                              hipStream_t stream) {
    const float* x    = (const float*)d_in[0];   // fp32 [N,256]
    const int*   ei   = (const int*)d_in[1];     // int32 [2,E]
    const float* W    = (const float*)d_in[2];   // fp32 [256,128]
    const float* bias = (const float*)d_in[3];   // fp32 [128]

    const int N = in_sizes[0] / N_FEAT;   // 100000
    const int E = in_sizes[1] / 2;        // 1600000

    // workspace layout (~34 MB)
    char* ws = (char*)d_ws;
    size_t off = 0;
    int*          deg    = (int*)(ws + off);   off += (size_t)N * 4;
    float*        dis    = (float*)(ws + off); off += (size_t)N * 4;
    int*          rowptr = (int*)(ws + off);   off += (size_t)(N + 1) * 4 + 12;
    int*          cursor = (int*)(ws + off);   off += (size_t)N * 4;
    int*          part   = (int*)(ws + off);   off += 512;
    int*          srcs   = (int*)(ws + off);   off += (size_t)E * 4;
    unsigned int* h2     = (unsigned int*)(ws + off);  // N*64 dwords (bf16 pairs)

    (void)hipMemsetAsync(deg, 0, (size_t)N * 4, stream);

    const int G = (N + 1023) / 1024;     // 98 scan blocks
    k_deg<<<(E + 255) / 256, 256, 0, stream>>>(ei, deg, E);
    k_scan_blocks<<<G, 256, 0, stream>>>(deg, part, N);
    k_scan_top<<<1, 64, 0, stream>>>(part, G, rowptr, N);
    k_scan_out<<<G, 256, 0, stream>>>(deg, part, rowptr, cursor, dis, N);
    k_bucket<<<(E + 255) / 256, 256, 0, stream>>>(ei, cursor, srcs, E);
    k_gemm<<<(N + BN - 1) / BN, 256, 0, stream>>>(x, W, dis, h2, N);
    k_aggr<<<(N + 3) / 4, 256, 0, stream>>>(rowptr, srcs, h2, dis, bias,
                                            (float2*)d_out, N);
}

// Round 6
// 380.879 us; speedup vs baseline: 2.6375x; 1.4006x over previous
//
#include <hip/hip_runtime.h>

// GCN scatter-aggregate:
//   h[n]   = bf16( dis[n] * (x[n] @ W) )    (fp32 compute, bf16 storage)
//   out[r] = dis[r] * sum_{e:dst=r} h[src_e] + bias  (fp32 accumulate,
//            atomic-free segment sum over dst-sorted edges)
// CSR build = 2-pass LDS-staged radix partition (no per-edge global atomics,
// line-friendly writes). Degrees/rowptr/dis fall out of the fine pass.
// Inputs: x fp32 [N,256], edge_index int32 [2,E] (row=dst, col=src),
//         W fp32 [256,128], bias fp32 [128]. Output fp32 [N,128].

#define N_FEAT 256
#define N_HID  128
#define BN 64      // nodes per gemm block
#define KC 64      // k-chunk staged in LDS
#define D_BITS 8   // coarse bucket = dst >> 8 (256 dsts/bucket)
#define NBMAX 392  // ceil(100000/256) = 391
#define CAP  6144  // per-bucket pair capacity (avg 4092, +16 sigma margin)
#define TILE 4096  // edges per k_part block

typedef float fx4 __attribute__((ext_vector_type(4)));

__device__ __forceinline__ float bf2f(unsigned int u) {
    return __uint_as_float(u << 16);
}
__device__ __forceinline__ unsigned int f2bf(float f) {
    unsigned int u = __float_as_uint(f);
    return (u + 0x7FFFu + ((u >> 16) & 1u)) >> 16;  // round-nearest-even
}

// ---- pass 1: partition edges into coarse buckets, LDS-staged ----------------
__global__ __launch_bounds__(256) void k_part(const int* __restrict__ ei,
                                              int* __restrict__ gcur,
                                              uint2* __restrict__ pairs,
                                              int E, int nb) {
    __shared__ int hist[NBMAX], lbase[NBMAX], gbase[NBMAX], cur[NBMAX];
    __shared__ int sc[256];
    __shared__ uint2 sorted[TILE];   // 32 KB
    const int t  = threadIdx.x;
    const int e0 = blockIdx.x * TILE;
    const int cnt = min(TILE, E - e0);

    for (int b = t; b < nb; b += 256) hist[b] = 0;
    __syncthreads();
    for (int i = t; i < cnt; i += 256)
        atomicAdd(&hist[ei[e0 + i] >> D_BITS], 1);
    __syncthreads();

    // exclusive scan of hist[0..nb), 2 elems/thread
    int v0 = (2 * t     < nb) ? hist[2 * t]     : 0;
    int v1 = (2 * t + 1 < nb) ? hist[2 * t + 1] : 0;
    sc[t] = v0 + v1;
    __syncthreads();
    for (int off = 1; off < 256; off <<= 1) {
        int a = sc[t];
        int b2 = (t >= off) ? sc[t - off] : 0;
        __syncthreads();
        sc[t] = a + b2;
        __syncthreads();
    }
    int ex = sc[t] - (v0 + v1);
    if (2 * t     < nb) lbase[2 * t]     = ex;
    if (2 * t + 1 < nb) lbase[2 * t + 1] = ex + v0;
    __syncthreads();

    // one global cursor atomic per (block,bucket); init LDS cursors
    for (int b = t; b < nb; b += 256) {
        int h = hist[b];
        gbase[b] = (h > 0) ? atomicAdd(&gcur[b], h) : 0;
        cur[b] = lbase[b];
    }
    __syncthreads();

    // bin (dst,src) pairs into LDS, bucket-sorted
    for (int i = t; i < cnt; i += 256) {
        int d = ei[e0 + i];
        int s = ei[E + e0 + i];
        int b = d >> D_BITS;
        int p = atomicAdd(&cur[b], 1);
        sorted[p] = make_uint2((unsigned)s, (unsigned)d);
    }
    __syncthreads();

    // copy out: contiguous runs per bucket -> line-friendly global writes
    for (int i = t; i < cnt; i += 256) {
        uint2 pr = sorted[i];
        int b = ((int)pr.y) >> D_BITS;
        pairs[(size_t)b * CAP + gbase[b] + (i - lbase[b])] = pr;
    }
}

// ---- scan of per-bucket totals -> bucket bases; rowptr[N]=E -----------------
__global__ __launch_bounds__(256) void k_scanb(const int* __restrict__ gcur,
                                               int* __restrict__ cbase,
                                               int* __restrict__ rowptr,
                                               int nb, int N, int E) {
    __shared__ int sc[256];
    int t = threadIdx.x;
    int v0 = (2 * t     < nb) ? gcur[2 * t]     : 0;
    int v1 = (2 * t + 1 < nb) ? gcur[2 * t + 1] : 0;
    sc[t] = v0 + v1;
    __syncthreads();
    for (int off = 1; off < 256; off <<= 1) {
        int a = sc[t];
        int b = (t >= off) ? sc[t - off] : 0;
        __syncthreads();
        sc[t] = a + b;
        __syncthreads();
    }
    int ex = sc[t] - (v0 + v1);
    if (2 * t     < nb) cbase[2 * t]     = ex;
    if (2 * t + 1 < nb) cbase[2 * t + 1] = ex + v0;
    if (t == 0) rowptr[N] = E;
}

// ---- pass 2: per-bucket counting sort; emits rowptr, dis, srcs --------------
__global__ __launch_bounds__(256) void k_fine(const uint2* __restrict__ pairs,
                                              const int* __restrict__ gcur,
                                              const int* __restrict__ cbase,
                                              int* __restrict__ rowptr,
                                              float* __restrict__ dis,
                                              int* __restrict__ srcs, int N) {
    __shared__ int hist[256], cur[256], sc[256];
    const int t = threadIdx.x;
    const int b = blockIdx.x;
    const int nbk  = gcur[b];
    const int base = cbase[b];
    const uint2* pp = pairs + (size_t)b * CAP;

    hist[t] = 0;
    __syncthreads();
    for (int i = t; i < nbk; i += 256)
        atomicAdd(&hist[pp[i].y & 255], 1);
    __syncthreads();

    int h = hist[t];
    sc[t] = h;
    __syncthreads();
    for (int off = 1; off < 256; off <<= 1) {
        int a = sc[t];
        int b2 = (t >= off) ? sc[t - off] : 0;
        __syncthreads();
        sc[t] = a + b2;
        __syncthreads();
    }
    int ex = sc[t] - h;
    cur[t] = ex;
    int d = (b << D_BITS) + t;
    if (d < N) {
        rowptr[d] = base + ex;
        dis[d] = (h > 0) ? rsqrtf((float)h) : 0.0f;
    }
    __syncthreads();

    for (int i = t; i < nbk; i += 256) {
        uint2 pr = pp[i];
        int p = atomicAdd(&cur[pr.y & 255], 1);
        srcs[base + p] = (int)pr.x;   // contiguous ~16KB region per block
    }
}

// ---- h = bf16(dis[n] * (x @ W)), tiled --------------------------------------
__global__ __launch_bounds__(256) void k_gemm(const float* __restrict__ x,
                                              const float* __restrict__ W,
                                              const float* __restrict__ dis,
                                              unsigned int* __restrict__ h2, int N) {
    __shared__ float xsT[KC * BN];   // 16 KB
    const int t  = threadIdx.x;
    const int cg = t & 31;
    const int ng = t >> 5;
    const int node0 = blockIdx.x * BN;

    float acc[8][4] = {};

    const fx4*    x4 = (const fx4*)x;
    const float4* W4 = (const float4*)W;

    for (int k0 = 0; k0 < N_FEAT; k0 += KC) {
        __syncthreads();
#pragma unroll
        for (int r = 0; r < 4; ++r) {
            int idx = t + 256 * r;
            int nd  = idx >> 4;
            int kq  = idx & 15;
            int gn  = node0 + nd;
            fx4 v = (gn < N)
                ? __builtin_nontemporal_load(&x4[gn * (N_FEAT / 4) + (k0 >> 2) + kq])
                : (fx4){0.f, 0.f, 0.f, 0.f};
            int kk = 4 * kq;
            int sn = nd ^ (8 * (kq & 7));
            xsT[(kk + 0) * BN + sn] = v.x;
            xsT[(kk + 1) * BN + sn] = v.y;
            xsT[(kk + 2) * BN + sn] = v.z;
            xsT[(kk + 3) * BN + sn] = v.w;
        }
        __syncthreads();

#pragma unroll 4
        for (int k = 0; k < KC; ++k) {
            float4 w = W4[(k0 + k) * (N_HID / 4) + cg];
            int s = 8 * ((k >> 2) & 7);
            const float* xr = &xsT[k * BN + ((8 * ng) ^ s)];
            float4 a = *(const float4*)(xr);
            float4 b = *(const float4*)(xr + 4);
            float xv[8] = {a.x, a.y, a.z, a.w, b.x, b.y, b.z, b.w};
#pragma unroll
            for (int n = 0; n < 8; ++n) {
                acc[n][0] = fmaf(xv[n], w.x, acc[n][0]);
                acc[n][1] = fmaf(xv[n], w.y, acc[n][1]);
                acc[n][2] = fmaf(xv[n], w.z, acc[n][2]);
                acc[n][3] = fmaf(xv[n], w.w, acc[n][3]);
            }
        }
    }

#pragma unroll
    for (int n = 0; n < 8; ++n) {
        int gn = node0 + 8 * ng + n;
        if (gn < N) {
            float dn = dis[gn];
            uint2 p;
            p.x = f2bf(dn * acc[n][0]) | (f2bf(dn * acc[n][1]) << 16);
            p.y = f2bf(dn * acc[n][2]) | (f2bf(dn * acc[n][3]) << 16);
            ((uint2*)h2)[(size_t)gn * 32 + cg] = p;
        }
    }
}

// ---- aggregation: out[n] = dis[n] * sum(h[srcs]) + bias ---------------------
__global__ __launch_bounds__(256) void k_aggr(const int* __restrict__ rowptr,
                                              const int* __restrict__ srcs,
                                              const unsigned int* __restrict__ h2,
                                              const float* __restrict__ dis,
                                              const float* __restrict__ bias,
                                              float2* __restrict__ out2, int N) {
    int n    = blockIdx.x * 4 + (threadIdx.x >> 6);
    int lane = threadIdx.x & 63;
    if (n >= N) return;
    int i   = rowptr[n];
    int end = rowptr[n + 1];
    float ax = 0.f, ay = 0.f;
    for (; i + 8 <= end; i += 8) {
        int c[8];
#pragma unroll
        for (int j = 0; j < 8; ++j) c[j] = srcs[i + j];
        unsigned int p[8];
#pragma unroll
        for (int j = 0; j < 8; ++j) p[j] = h2[(size_t)c[j] * 64 + lane];
#pragma unroll
        for (int j = 0; j < 8; ++j) {
            ax += bf2f(p[j] & 0xFFFFu);
            ay += bf2f(p[j] >> 16);
        }
    }
    for (; i < end; ++i) {
        unsigned int p = h2[(size_t)srcs[i] * 64 + lane];
        ax += bf2f(p & 0xFFFFu);
        ay += bf2f(p >> 16);
    }
    float dn = dis[n];
    float2 b = ((const float2*)bias)[lane];
    float2 o; o.x = dn * ax + b.x; o.y = dn * ay + b.y;
    out2[(size_t)n * 64 + lane] = o;
}

extern "C" void kernel_launch(void* const* d_in, const int* in_sizes, int n_in,
                              void* d_out, int out_size, void* d_ws, size_t ws_size,
                              hipStream_t stream) {
    const float* x    = (const float*)d_in[0];   // fp32 [N,256]
    const int*   ei   = (const int*)d_in[1];     // int32 [2,E]
    const float* W    = (const float*)d_in[2];   // fp32 [256,128]
    const float* bias = (const float*)d_in[3];   // fp32 [128]

    const int N = in_sizes[0] / N_FEAT;   // 100000
    const int E = in_sizes[1] / 2;        // 1600000
    const int nb = (N + 255) >> D_BITS;   // 391 coarse buckets

    // workspace layout (~52 MB)
    char* ws = (char*)d_ws;
    size_t off = 0;
    int*          gcur   = (int*)(ws + off);   off += 512 * 4;
    int*          cbase  = (int*)(ws + off);   off += 512 * 4;
    int*          rowptr = (int*)(ws + off);   off += (size_t)(N + 1) * 4 + 12;
    float*        dis    = (float*)(ws + off); off += (size_t)N * 4;
    int*          srcs   = (int*)(ws + off);   off += (size_t)E * 4;
    uint2*        pairs  = (uint2*)(ws + off); off += (size_t)nb * CAP * 8;
    unsigned int* h2     = (unsigned int*)(ws + off);  // N*64 dwords (bf16 pairs)

    (void)hipMemsetAsync(gcur, 0, (size_t)nb * 4, stream);

    k_part<<<(E + TILE - 1) / TILE, 256, 0, stream>>>(ei, gcur, pairs, E, nb);
    k_scanb<<<1, 256, 0, stream>>>(gcur, cbase, rowptr, nb, N, E);
    k_fine<<<nb, 256, 0, stream>>>(pairs, gcur, cbase, rowptr, dis, srcs, N);
    k_gemm<<<(N + BN - 1) / BN, 256, 0, stream>>>(x, W, dis, h2, N);
    k_aggr<<<(N + 3) / 4, 256, 0, stream>>>(rowptr, srcs, h2, dis, bias,
                                            (float2*)d_out, N);
}

// Round 7
// 325.077 us; speedup vs baseline: 3.0902x; 1.1717x over previous
//
#include <hip/hip_runtime.h>

// GCN scatter-aggregate:
//   h[n]   = bf16( dis[n] * (x[n] @ W) )    -- MFMA bf16, fp32 accumulate
//   out[r] = dis[r] * sum_{e:dst=r} h[src_e] + bias  (fp32 accumulate,
//            atomic-free segment sum over dst-sorted edges)
// CSR build = 2-pass LDS-staged radix partition (round 6, unchanged).
// Inputs: x fp32 [N,256], edge_index int32 [2,E] (row=dst, col=src),
//         W fp32 [256,128], bias fp32 [128]. Output fp32 [N,128].

#define N_FEAT 256
#define N_HID  128
#define D_BITS 8   // coarse bucket = dst >> 8 (256 dsts/bucket)
#define NBMAX 392  // ceil(100000/256) = 391
#define CAP  6144  // per-bucket pair capacity (avg 4092, +16 sigma margin)
#define TILE 4096  // edges per k_part block

typedef float fx4    __attribute__((ext_vector_type(4)));
typedef float f32x16 __attribute__((ext_vector_type(16)));
typedef short bf16x8 __attribute__((ext_vector_type(8)));

__device__ __forceinline__ float bf2f(unsigned int u) {
    return __uint_as_float(u << 16);
}
__device__ __forceinline__ unsigned int f2bf(float f) {
    unsigned int u = __float_as_uint(f);
    return (u + 0x7FFFu + ((u >> 16) & 1u)) >> 16;  // round-nearest-even
}

// ---- pass 1: partition edges into coarse buckets, LDS-staged ----------------
__global__ __launch_bounds__(256) void k_part(const int* __restrict__ ei,
                                              int* __restrict__ gcur,
                                              uint2* __restrict__ pairs,
                                              int E, int nb) {
    __shared__ int hist[NBMAX], lbase[NBMAX], gbase[NBMAX], cur[NBMAX];
    __shared__ int sc[256];
    __shared__ uint2 sorted[TILE];   // 32 KB
    const int t  = threadIdx.x;
    const int e0 = blockIdx.x * TILE;
    const int cnt = min(TILE, E - e0);

    for (int b = t; b < nb; b += 256) hist[b] = 0;
    __syncthreads();
    for (int i = t; i < cnt; i += 256)
        atomicAdd(&hist[ei[e0 + i] >> D_BITS], 1);
    __syncthreads();

    int v0 = (2 * t     < nb) ? hist[2 * t]     : 0;
    int v1 = (2 * t + 1 < nb) ? hist[2 * t + 1] : 0;
    sc[t] = v0 + v1;
    __syncthreads();
    for (int off = 1; off < 256; off <<= 1) {
        int a = sc[t];
        int b2 = (t >= off) ? sc[t - off] : 0;
        __syncthreads();
        sc[t] = a + b2;
        __syncthreads();
    }
    int ex = sc[t] - (v0 + v1);
    if (2 * t     < nb) lbase[2 * t]     = ex;
    if (2 * t + 1 < nb) lbase[2 * t + 1] = ex + v0;
    __syncthreads();

    for (int b = t; b < nb; b += 256) {
        int h = hist[b];
        gbase[b] = (h > 0) ? atomicAdd(&gcur[b], h) : 0;
        cur[b] = lbase[b];
    }
    __syncthreads();

    for (int i = t; i < cnt; i += 256) {
        int d = ei[e0 + i];
        int s = ei[E + e0 + i];
        int b = d >> D_BITS;
        int p = atomicAdd(&cur[b], 1);
        sorted[p] = make_uint2((unsigned)s, (unsigned)d);
    }
    __syncthreads();

    for (int i = t; i < cnt; i += 256) {
        uint2 pr = sorted[i];
        int b = ((int)pr.y) >> D_BITS;
        pairs[(size_t)b * CAP + gbase[b] + (i - lbase[b])] = pr;
    }
}

// ---- scan of per-bucket totals -> bucket bases; rowptr[N]=E -----------------
__global__ __launch_bounds__(256) void k_scanb(const int* __restrict__ gcur,
                                               int* __restrict__ cbase,
                                               int* __restrict__ rowptr,
                                               int nb, int N, int E) {
    __shared__ int sc[256];
    int t = threadIdx.x;
    int v0 = (2 * t     < nb) ? gcur[2 * t]     : 0;
    int v1 = (2 * t + 1 < nb) ? gcur[2 * t + 1] : 0;
    sc[t] = v0 + v1;
    __syncthreads();
    for (int off = 1; off < 256; off <<= 1) {
        int a = sc[t];
        int b = (t >= off) ? sc[t - off] : 0;
        __syncthreads();
        sc[t] = a + b;
        __syncthreads();
    }
    int ex = sc[t] - (v0 + v1);
    if (2 * t     < nb) cbase[2 * t]     = ex;
    if (2 * t + 1 < nb) cbase[2 * t + 1] = ex + v0;
    if (t == 0) rowptr[N] = E;
}

// ---- pass 2: per-bucket counting sort; emits rowptr, dis, srcs --------------
__global__ __launch_bounds__(256) void k_fine(const uint2* __restrict__ pairs,
                                              const int* __restrict__ gcur,
                                              const int* __restrict__ cbase,
                                              int* __restrict__ rowptr,
                                              float* __restrict__ dis,
                                              int* __restrict__ srcs, int N) {
    __shared__ int hist[256], cur[256], sc[256];
    const int t = threadIdx.x;
    const int b = blockIdx.x;
    const int nbk  = gcur[b];
    const int base = cbase[b];
    const uint2* pp = pairs + (size_t)b * CAP;

    hist[t] = 0;
    __syncthreads();
    for (int i = t; i < nbk; i += 256)
        atomicAdd(&hist[pp[i].y & 255], 1);
    __syncthreads();

    int h = hist[t];
    sc[t] = h;
    __syncthreads();
    for (int off = 1; off < 256; off <<= 1) {
        int a = sc[t];
        int b2 = (t >= off) ? sc[t - off] : 0;
        __syncthreads();
        sc[t] = a + b2;
        __syncthreads();
    }
    int ex = sc[t] - h;
    cur[t] = ex;
    int d = (b << D_BITS) + t;
    if (d < N) {
        rowptr[d] = base + ex;
        dis[d] = (h > 0) ? rsqrtf((float)h) : 0.0f;
    }
    __syncthreads();

    for (int i = t; i < nbk; i += 256) {
        uint2 pr = pp[i];
        int p = atomicAdd(&cur[pr.y & 255], 1);
        srcs[base + p] = (int)pr.x;
    }
}

// ---- W -> fragment-ready bf16 (B-operand of mfma_f32_32x32x16_bf16) ---------
// Frag f = kstep*4 + ntile; lane supplies B[k=kstep*16+(lane>>5)*8+j][n=ntile*32+(lane&31)].
__global__ __launch_bounds__(256) void k_wconv(const float* __restrict__ W,
                                               uint4* __restrict__ Wf) {
    int i = blockIdx.x * 256 + threadIdx.x;   // 0..4095
    int lane = i & 63, f = i >> 6;
    int kstep = f >> 2, nt = f & 3;
    int n  = nt * 32 + (lane & 31);
    int kb = kstep * 16 + (lane >> 5) * 8;
    unsigned s[8];
#pragma unroll
    for (int j = 0; j < 8; ++j) s[j] = f2bf(W[(kb + j) * N_HID + n]);
    uint4 o;
    o.x = s[0] | (s[1] << 16);
    o.y = s[2] | (s[3] << 16);
    o.z = s[4] | (s[5] << 16);
    o.w = s[6] | (s[7] << 16);
    Wf[i] = o;
}

// ---- h = bf16(dis[n] * (x @ W)) via MFMA, no LDS ----------------------------
// Block = 4 waves; wave w covers rows mbase+w*32 .. +31, all 128 cols.
__global__ __launch_bounds__(256) void k_gemm(const float* __restrict__ x,
                                              const uint4* __restrict__ Wf,
                                              const float* __restrict__ dis,
                                              unsigned short* __restrict__ h2s,
                                              int N) {
    const int wave = threadIdx.x >> 6;
    const int lane = threadIdx.x & 63;
    const int half = lane >> 5;          // k sub-block 0/1 (8 elems each)
    const int lm   = lane & 31;
    const int mbase = blockIdx.x * 128 + wave * 32;
    const int arow  = min(mbase + lm, N - 1);   // clamp; garbage rows discarded

    const fx4* xr = (const fx4*)(x + (size_t)arow * N_FEAT) + half * 2;

    f32x16 acc0 = {0}, acc1 = {0}, acc2 = {0}, acc3 = {0};

#pragma unroll
    for (int ks = 0; ks < 16; ++ks) {
        fx4 a0 = xr[ks * 4];          // k = ks*16 + half*8 + (0..3)
        fx4 a1 = xr[ks * 4 + 1];      //                  + (4..7)
        union { bf16x8 v; unsigned u[4]; } A;
        A.u[0] = f2bf(a0.x) | (f2bf(a0.y) << 16);
        A.u[1] = f2bf(a0.z) | (f2bf(a0.w) << 16);
        A.u[2] = f2bf(a1.x) | (f2bf(a1.y) << 16);
        A.u[3] = f2bf(a1.z) | (f2bf(a1.w) << 16);
        union { bf16x8 v; uint4 q; } B0, B1, B2, B3;
        B0.q = Wf[(ks * 4 + 0) * 64 + lane];
        B1.q = Wf[(ks * 4 + 1) * 64 + lane];
        B2.q = Wf[(ks * 4 + 2) * 64 + lane];
        B3.q = Wf[(ks * 4 + 3) * 64 + lane];
        acc0 = __builtin_amdgcn_mfma_f32_32x32x16_bf16(A.v, B0.v, acc0, 0, 0, 0);
        acc1 = __builtin_amdgcn_mfma_f32_32x32x16_bf16(A.v, B1.v, acc1, 0, 0, 0);
        acc2 = __builtin_amdgcn_mfma_f32_32x32x16_bf16(A.v, B2.v, acc2, 0, 0, 0);
        acc3 = __builtin_amdgcn_mfma_f32_32x32x16_bf16(A.v, B3.v, acc3, 0, 0, 0);
    }

    // C/D: col = lane&31, row = (r&3) + 8*(r>>2) + 4*(lane>>5)   [m74/m101]
#pragma unroll
    for (int r = 0; r < 16; ++r) {
        int row  = (r & 3) + 8 * (r >> 2) + 4 * half;
        int node = mbase + row;
        if (node < N) {
            float dn = dis[node];
            size_t o = (size_t)node * N_HID + lm;
            h2s[o +  0] = (unsigned short)f2bf(dn * acc0[r]);
            h2s[o + 32] = (unsigned short)f2bf(dn * acc1[r]);
            h2s[o + 64] = (unsigned short)f2bf(dn * acc2[r]);
            h2s[o + 96] = (unsigned short)f2bf(dn * acc3[r]);
        }
    }
}

// ---- aggregation: out[n] = dis[n] * sum(h[srcs]) + bias ---------------------
__global__ __launch_bounds__(256) void k_aggr(const int* __restrict__ rowptr,
                                              const int* __restrict__ srcs,
                                              const unsigned int* __restrict__ h2,
                                              const float* __restrict__ dis,
                                              const float* __restrict__ bias,
                                              float2* __restrict__ out2, int N) {
    int n    = blockIdx.x * 4 + (threadIdx.x >> 6);
    int lane = threadIdx.x & 63;
    if (n >= N) return;
    int i   = rowptr[n];
    int end = rowptr[n + 1];
    float ax = 0.f, ay = 0.f;
    for (; i + 8 <= end; i += 8) {
        int c[8];
#pragma unroll
        for (int j = 0; j < 8; ++j) c[j] = srcs[i + j];
        unsigned int p[8];
#pragma unroll
        for (int j = 0; j < 8; ++j) p[j] = h2[(size_t)c[j] * 64 + lane];
#pragma unroll
        for (int j = 0; j < 8; ++j) {
            ax += bf2f(p[j] & 0xFFFFu);
            ay += bf2f(p[j] >> 16);
        }
    }
    for (; i < end; ++i) {
        unsigned int p = h2[(size_t)srcs[i] * 64 + lane];
        ax += bf2f(p & 0xFFFFu);
        ay += bf2f(p >> 16);
    }
    float dn = dis[n];
    float2 b = ((const float2*)bias)[lane];
    float2 o; o.x = dn * ax + b.x; o.y = dn * ay + b.y;
    out2[(size_t)n * 64 + lane] = o;
}

extern "C" void kernel_launch(void* const* d_in, const int* in_sizes, int n_in,
                              void* d_out, int out_size, void* d_ws, size_t ws_size,
                              hipStream_t stream) {
    const float* x    = (const float*)d_in[0];   // fp32 [N,256]
    const int*   ei   = (const int*)d_in[1];     // int32 [2,E]
    const float* W    = (const float*)d_in[2];   // fp32 [256,128]
    const float* bias = (const float*)d_in[3];   // fp32 [128]

    const int N = in_sizes[0] / N_FEAT;   // 100000
    const int E = in_sizes[1] / 2;        // 1600000
    const int nb = (N + 255) >> D_BITS;   // 391 coarse buckets

    // workspace layout (~52 MB)
    char* ws = (char*)d_ws;
    size_t off = 0;
    int*          gcur   = (int*)(ws + off);   off += 512 * 4;
    int*          cbase  = (int*)(ws + off);   off += 512 * 4;
    int*          rowptr = (int*)(ws + off);   off += (size_t)(N + 1) * 4 + 12;
    float*        dis    = (float*)(ws + off); off += (size_t)N * 4;
    int*          srcs   = (int*)(ws + off);   off += (size_t)E * 4;
    uint4*        Wf     = (uint4*)(ws + off); off += 4096 * 16;   // 64 KB
    uint2*        pairs  = (uint2*)(ws + off); off += (size_t)nb * CAP * 8;
    unsigned int* h2     = (unsigned int*)(ws + off);  // N*64 dwords (bf16 pairs)

    (void)hipMemsetAsync(gcur, 0, (size_t)nb * 4, stream);

    k_wconv<<<16, 256, 0, stream>>>(W, Wf);
    k_part<<<(E + TILE - 1) / TILE, 256, 0, stream>>>(ei, gcur, pairs, E, nb);
    k_scanb<<<1, 256, 0, stream>>>(gcur, cbase, rowptr, nb, N, E);
    k_fine<<<nb, 256, 0, stream>>>(pairs, gcur, cbase, rowptr, dis, srcs, N);
    k_gemm<<<(N + 127) / 128, 256, 0, stream>>>(x, Wf, dis,
                                                (unsigned short*)h2, N);
    k_aggr<<<(N + 3) / 4, 256, 0, stream>>>(rowptr, srcs, h2, dis, bias,
                                            (float2*)d_out, N);
}